// Round 3
// baseline (219.794 us; speedup 1.0000x reference)
//
#include <hip/hip_runtime.h>
#include <hip/hip_bf16.h>

#define HIDDEN 512
#define M_PER_TOKEN 32
#define M_PER_BLOCK 16      // 2 blocks per token
#define ROWS_PER_WAVE 4     // 4 waves x 4 rows = 16

typedef __attribute__((address_space(3))) float lds_f;
typedef const __attribute__((address_space(1))) float glb_f;

// v3: async global->LDS gather (zero VGPR payload, 8 x 1KB in flight per
// wave), 16 m per block, 32KB LDS -> 5 blocks/CU. Attacks the measured
// latency-bound behavior (replay passes showed hbm_bytes ~1.2MB at identical
// dur -> HBM irrelevant; ~1 load in flight per wave in v1/v2).
__global__ __launch_bounds__(256) void dynamic_ffn_kernel(
    const float* __restrict__ input,    // [8192, 512]
    const int*   __restrict__ mask,     // [8192, 32]
    const float* __restrict__ weight,   // [50000, 512]
    const float* __restrict__ bias,     // [50000]
    float*       __restrict__ out,      // [8192, 32]
    int n_tokens)
{
    __shared__ float lds_w[M_PER_BLOCK][HIDDEN];   // 32 KB, NO padding:
    // global_load_lds lands lane i's 16B at base + i*16 — layout must be
    // contiguous in lane order.

    const int token = blockIdx.x >> 1;
    const int half  = blockIdx.x & 1;
    const int wave  = threadIdx.x >> 6;   // 0..3
    const int lane  = threadIdx.x & 63;   // 0..63
    const int m0    = half * M_PER_BLOCK + wave * ROWS_PER_WAVE; // token-m base
    const int r0    = wave * ROWS_PER_WAVE;                      // LDS row base

    const int* midx = mask + (size_t)token * M_PER_TOKEN + m0;
    int idx[ROWS_PER_WAVE];
#pragma unroll
    for (int j = 0; j < ROWS_PER_WAVE; ++j) idx[j] = midx[j];

    // Issue ALL async gathers back-to-back: 2 x 1KB per row, 8 per wave.
    // No VGPR destination -> compiler cannot serialize them.
#pragma unroll
    for (int j = 0; j < ROWS_PER_WAVE; ++j) {
        const float* gsrc = weight + (size_t)idx[j] * HIDDEN + lane * 4;
#pragma unroll
        for (int c = 0; c < 2; ++c) {
            __builtin_amdgcn_global_load_lds(
                (glb_f*)(gsrc + c * 256),
                (lds_f*)&lds_w[r0 + j][c * 256],
                16, 0, 0);
        }
    }

    // Independent work while gathers fly: input slice (L1/L2 hit after the
    // first block touches the row).
    const float* in_row = input + (size_t)token * HIDDEN + lane * 8;
    const float4 x0 = *(const float4*)(in_row);
    const float4 x1 = *(const float4*)(in_row + 4);

    __syncthreads();   // s_waitcnt vmcnt(0) + barrier: LDS data now visible

    float* orow = out + (size_t)token * M_PER_TOKEN + m0;
#pragma unroll
    for (int j = 0; j < ROWS_PER_WAVE; ++j) {
        const float4 w0 = *(const float4*)&lds_w[r0 + j][lane * 8];
        const float4 w1 = *(const float4*)&lds_w[r0 + j][lane * 8 + 4];
        float p = x0.x * w0.x + x0.y * w0.y + x0.z * w0.z + x0.w * w0.w
                + x1.x * w1.x + x1.y * w1.y + x1.z * w1.z + x1.w * w1.w;
#pragma unroll
        for (int off = 32; off > 0; off >>= 1)
            p += __shfl_down(p, off, 64);
        if (lane == 0) {
            float r = p + bias[idx[j]];
            orow[j] = r > 0.0f ? r : 0.0f;
        }
    }
}

extern "C" void kernel_launch(void* const* d_in, const int* in_sizes, int n_in,
                              void* d_out, int out_size, void* d_ws, size_t ws_size,
                              hipStream_t stream) {
    const float* input  = (const float*)d_in[0];   // [4,2048,512] fp32
    const int*   mask   = (const int*)  d_in[1];   // [4,2048,32] int32
    const float* weight = (const float*)d_in[2];   // [50000,512] fp32
    const float* bias   = (const float*)d_in[3];   // [50000] fp32
    float*       out    = (float*)d_out;           // [4,2048,32] fp32

    const int n_tokens = in_sizes[0] / HIDDEN;     // 8192

    dynamic_ffn_kernel<<<n_tokens * 2, 256, 0, stream>>>(
        input, mask, weight, bias, out, n_tokens);
}

// Round 4
// 213.115 us; speedup vs baseline: 1.0313x; 1.0313x over previous
//
#include <hip/hip_runtime.h>
#include <hip/hip_bf16.h>

#define HIDDEN 512
#define M_PER_TOKEN 32

typedef _Float16 half8 __attribute__((ext_vector_type(8)));

// ---------------------------------------------------------------------------
// Kernel 1: fp32 weight table -> fp16 table in workspace (51.2 MB).
// Streaming: each thread converts one 8-element chunk (read 32B, write 16B).
// ---------------------------------------------------------------------------
__global__ __launch_bounds__(256) void convert_w_kernel(
    const float* __restrict__ w,        // [50000*512]
    _Float16*    __restrict__ wh,       // [50000*512]
    int n_chunks)                       // 50000*512/8
{
    int i = blockIdx.x * 256 + threadIdx.x;
    if (i >= n_chunks) return;
    const float4 a = ((const float4*)w)[2 * i];
    const float4 b = ((const float4*)w)[2 * i + 1];
    half8 h;
    h[0] = (_Float16)a.x; h[1] = (_Float16)a.y;
    h[2] = (_Float16)a.z; h[3] = (_Float16)a.w;
    h[4] = (_Float16)b.x; h[5] = (_Float16)b.y;
    h[6] = (_Float16)b.z; h[7] = (_Float16)b.w;
    ((half8*)wh)[i] = h;
}

// ---------------------------------------------------------------------------
// Kernel 2: gather + dot from the fp16 table.
// One block (4 waves) per token; wave w owns m = w*8..w*8+7.
// fp16 row = 1KB: lane's 16B slice = 8 halves = ONE dwordx4 per (m,lane).
// Halves the bytes through the ~2.8 TB/s L2-fill wall (the measured
// bottleneck: FETCH_SIZE/2.8TB/s == dur across rounds 1-3).
// ---------------------------------------------------------------------------
__global__ __launch_bounds__(256) void dynamic_ffn_f16_kernel(
    const float*    __restrict__ input,   // [8192, 512] fp32
    const int*      __restrict__ mask,    // [8192, 32]
    const _Float16* __restrict__ wh,      // [50000, 512] fp16
    const float*    __restrict__ bias,    // [50000] fp32
    float*          __restrict__ out,     // [8192, 32]
    int n_tokens)
{
    const int token = blockIdx.x;
    if (token >= n_tokens) return;

    const int wave = threadIdx.x >> 6;
    const int lane = threadIdx.x & 63;

    // Input slice (fp32, stays in registers; block's 4 waves share via L1).
    const float* in_row = input + (size_t)token * HIDDEN + lane * 8;
    const float4 x0 = *(const float4*)(in_row);
    const float4 x1 = *(const float4*)(in_row + 4);

    const int* midx = mask + (size_t)token * M_PER_TOKEN + wave * 8;
    float*     orow = out  + (size_t)token * M_PER_TOKEN + wave * 8;

    int idx[8];
#pragma unroll
    for (int j = 0; j < 8; ++j) idx[j] = midx[j];

    // 8 gathers (one dwordx4 each = 32 VGPRs payload) -> dots.
    // (float)h * float fuses to v_fma_mix_f32.
    float acc[8];
#pragma unroll
    for (int j = 0; j < 8; ++j) {
        const half8 h = *(const half8*)(wh + (size_t)idx[j] * HIDDEN + lane * 8);
        acc[j] = (float)h[0] * x0.x + (float)h[1] * x0.y
               + (float)h[2] * x0.z + (float)h[3] * x0.w
               + (float)h[4] * x1.x + (float)h[5] * x1.y
               + (float)h[6] * x1.z + (float)h[7] * x1.w;
    }

#pragma unroll
    for (int j = 0; j < 8; ++j) {
        float p = acc[j];
#pragma unroll
        for (int off = 32; off > 0; off >>= 1)
            p += __shfl_down(p, off, 64);
        if (lane == 0) {
            float r = p + bias[idx[j]];
            orow[j] = r > 0.0f ? r : 0.0f;
        }
    }
}

// ---------------------------------------------------------------------------
// Fallback (ws too small): round-1 fp32 kernel, known-good at 97us.
// ---------------------------------------------------------------------------
__global__ __launch_bounds__(256) void dynamic_ffn_f32_kernel(
    const float* __restrict__ input,
    const int*   __restrict__ mask,
    const float* __restrict__ weight,
    const float* __restrict__ bias,
    float*       __restrict__ out,
    int n_tokens)
{
    const int token = blockIdx.x;
    if (token >= n_tokens) return;
    const int wave = threadIdx.x >> 6;
    const int lane = threadIdx.x & 63;

    const float* in_row = input + (size_t)token * HIDDEN + lane * 8;
    const float4 x0 = *(const float4*)(in_row);
    const float4 x1 = *(const float4*)(in_row + 4);

    const int* midx = mask + (size_t)token * M_PER_TOKEN + wave * 8;
    float*     orow = out  + (size_t)token * M_PER_TOKEN + wave * 8;

    int idx[8];
#pragma unroll
    for (int j = 0; j < 8; ++j) idx[j] = midx[j];

    float acc[8];
#pragma unroll
    for (int j = 0; j < 8; ++j) {
        const float* w = weight + (size_t)idx[j] * HIDDEN + lane * 8;
        const float4 w0 = *(const float4*)(w);
        const float4 w1 = *(const float4*)(w + 4);
        acc[j] = x0.x * w0.x + x0.y * w0.y + x0.z * w0.z + x0.w * w0.w
               + x1.x * w1.x + x1.y * w1.y + x1.z * w1.z + x1.w * w1.w;
    }
#pragma unroll
    for (int j = 0; j < 8; ++j) {
        float p = acc[j];
#pragma unroll
        for (int off = 32; off > 0; off >>= 1)
            p += __shfl_down(p, off, 64);
        if (lane == 0) {
            float r = p + bias[idx[j]];
            orow[j] = r > 0.0f ? r : 0.0f;
        }
    }
}

extern "C" void kernel_launch(void* const* d_in, const int* in_sizes, int n_in,
                              void* d_out, int out_size, void* d_ws, size_t ws_size,
                              hipStream_t stream) {
    const float* input  = (const float*)d_in[0];   // [4,2048,512] fp32
    const int*   mask   = (const int*)  d_in[1];   // [4,2048,32] int32
    const float* weight = (const float*)d_in[2];   // [50000,512] fp32
    const float* bias   = (const float*)d_in[3];   // [50000] fp32
    float*       out    = (float*)d_out;           // [4,2048,32] fp32

    const int n_tokens  = in_sizes[0] / HIDDEN;    // 8192
    const int w_elems   = in_sizes[2];             // 50000*512
    const size_t need   = (size_t)w_elems * sizeof(_Float16);

    if (ws_size >= need) {
        _Float16* wh = (_Float16*)d_ws;
        const int n_chunks = w_elems / 8;          // 3,200,000
        convert_w_kernel<<<(n_chunks + 255) / 256, 256, 0, stream>>>(
            weight, wh, n_chunks);
        dynamic_ffn_f16_kernel<<<n_tokens, 256, 0, stream>>>(
            input, mask, wh, bias, out, n_tokens);
    } else {
        dynamic_ffn_f32_kernel<<<n_tokens, 256, 0, stream>>>(
            input, mask, weight, bias, out, n_tokens);
    }
}

// Round 5
// 205.317 us; speedup vs baseline: 1.0705x; 1.0380x over previous
//
#include <hip/hip_runtime.h>
#include <hip/hip_bf16.h>

#define HIDDEN 512
#define M_PER_TOKEN 32
#define BUCKET_CAP 32   // Poisson(5.24) users/row; P(>32) ~ 1e-11 for 50k rows

typedef _Float16 half8 __attribute__((ext_vector_type(8)));

// ---------------------------------------------------------------------------
// K1: input fp32 -> fp16 (8.4 MB table, the new GATHERED side) + zero counts.
// ---------------------------------------------------------------------------
__global__ __launch_bounds__(256) void prep_kernel(
    const float* __restrict__ input,   // [8192*512]
    _Float16*    __restrict__ in_h,    // [8192*512]
    int*         __restrict__ counts,  // [n_rows]
    int n_chunks, int n_rows)
{
    int i = blockIdx.x * 256 + threadIdx.x;
    if (i < n_chunks) {
        const float4 a = ((const float4*)input)[2 * i];
        const float4 b = ((const float4*)input)[2 * i + 1];
        half8 h;
        h[0] = (_Float16)a.x; h[1] = (_Float16)a.y;
        h[2] = (_Float16)a.z; h[3] = (_Float16)a.w;
        h[4] = (_Float16)b.x; h[5] = (_Float16)b.y;
        h[6] = (_Float16)b.z; h[7] = (_Float16)b.w;
        ((half8*)in_h)[i] = h;
    }
    if (i < n_rows) counts[i] = 0;
}

// ---------------------------------------------------------------------------
// K2: inverted index. pair i -> row r = mask[i]; bucket slot via atomicAdd.
// padded[r*32 + slot] = i  (i encodes token = i>>5, m = i&31 = out index).
// ---------------------------------------------------------------------------
__global__ __launch_bounds__(256) void scatter_kernel(
    const int* __restrict__ mask,     // [262144]
    int*       __restrict__ counts,   // [n_rows]
    int*       __restrict__ padded,   // [n_rows*32]
    int n_pairs)
{
    int i = blockIdx.x * 256 + threadIdx.x;
    if (i >= n_pairs) return;
    int r = mask[i];
    int slot = atomicAdd(&counts[r], 1);
    if (slot < BUCKET_CAP) padded[(r << 5) + slot] = i;
}

// ---------------------------------------------------------------------------
// K3: row-centric main. One wave per weight row:
//  - weight row read SEQUENTIALLY once (fp32, streaming - no MSHR wall)
//  - per user: gather 1KB fp16 input row (8.4MB working set, L2-hit-rich)
//  - dot via fma_mix, 64-lane reduce, lane0 scatters relu(dot+bias[r]).
// Block b swizzled so each XCD streams a CONTIGUOUS weight slice.
// ---------------------------------------------------------------------------
__global__ __launch_bounds__(256) void row_ffn_kernel(
    const _Float16* __restrict__ in_h,    // [8192, 512] fp16
    const float*    __restrict__ weight,  // [n_rows, 512] fp32
    const float*    __restrict__ bias,    // [n_rows]
    const int*      __restrict__ counts,  // [n_rows]
    const int*      __restrict__ padded,  // [n_rows, 32]
    float*          __restrict__ out,     // [8192, 32]
    int n_rows, int blocks_per_xcd)
{
    // XCD-contiguous swizzle: blocks with (b&7)==k cover a contiguous range.
    const int b    = (int)blockIdx.x;
    const int bsw  = (b & 7) * blocks_per_xcd + (b >> 3);
    const int wave = threadIdx.x >> 6;
    const int lane = threadIdx.x & 63;
    const int r    = bsw * 4 + wave;
    if (r >= n_rows) return;

    int c = counts[r];
    if (c <= 0) return;
    if (c > BUCKET_CAP) c = BUCKET_CAP;

    // Weight row: lane owns 8 floats (32B); wave = full 2KB row, sequential
    // across waves/blocks -> pure streaming.
    const float* wrow = weight + (size_t)r * HIDDEN + lane * 8;
    const float4 w0 = *(const float4*)(wrow);
    const float4 w1 = *(const float4*)(wrow + 4);
    const float  bv = bias[r];

    const int* users = padded + (r << 5);

    // Chunks of 4 users: one int4 uniform load for ids, 4 independent 16B
    // input gathers in flight, then 4 dot+reduce.
    int u = 0;
    for (; u + 4 <= c; u += 4) {
        const int4 p = *(const int4*)(users + u);
        const half8 h0 = *(const half8*)(in_h + (size_t)(p.x >> 5) * HIDDEN + lane * 8);
        const half8 h1 = *(const half8*)(in_h + (size_t)(p.y >> 5) * HIDDEN + lane * 8);
        const half8 h2 = *(const half8*)(in_h + (size_t)(p.z >> 5) * HIDDEN + lane * 8);
        const half8 h3 = *(const half8*)(in_h + (size_t)(p.w >> 5) * HIDDEN + lane * 8);
        int   pid[4] = {p.x, p.y, p.z, p.w};
        half8 hh[4]  = {h0, h1, h2, h3};
#pragma unroll
        for (int k = 0; k < 4; ++k) {
            const half8 h = hh[k];
            float d = (float)h[0] * w0.x + (float)h[1] * w0.y
                    + (float)h[2] * w0.z + (float)h[3] * w0.w
                    + (float)h[4] * w1.x + (float)h[5] * w1.y
                    + (float)h[6] * w1.z + (float)h[7] * w1.w;
#pragma unroll
            for (int off = 32; off > 0; off >>= 1)
                d += __shfl_down(d, off, 64);
            if (lane == 0) {
                float v = d + bv;
                out[pid[k]] = v > 0.0f ? v : 0.0f;
            }
        }
    }
    for (; u < c; ++u) {
        const int p = users[u];
        const half8 h = *(const half8*)(in_h + (size_t)(p >> 5) * HIDDEN + lane * 8);
        float d = (float)h[0] * w0.x + (float)h[1] * w0.y
                + (float)h[2] * w0.z + (float)h[3] * w0.w
                + (float)h[4] * w1.x + (float)h[5] * w1.y
                + (float)h[6] * w1.z + (float)h[7] * w1.w;
#pragma unroll
        for (int off = 32; off > 0; off >>= 1)
            d += __shfl_down(d, off, 64);
        if (lane == 0) {
            float v = d + bv;
            out[p] = v > 0.0f ? v : 0.0f;
        }
    }
}

// ---------------------------------------------------------------------------
// Fallback (ws too small): round-1 fp32 token-centric, known-good 97us.
// ---------------------------------------------------------------------------
__global__ __launch_bounds__(256) void dynamic_ffn_f32_kernel(
    const float* __restrict__ input,
    const int*   __restrict__ mask,
    const float* __restrict__ weight,
    const float* __restrict__ bias,
    float*       __restrict__ out,
    int n_tokens)
{
    const int token = blockIdx.x;
    if (token >= n_tokens) return;
    const int wave = threadIdx.x >> 6;
    const int lane = threadIdx.x & 63;

    const float* in_row = input + (size_t)token * HIDDEN + lane * 8;
    const float4 x0 = *(const float4*)(in_row);
    const float4 x1 = *(const float4*)(in_row + 4);

    const int* midx = mask + (size_t)token * M_PER_TOKEN + wave * 8;
    float*     orow = out  + (size_t)token * M_PER_TOKEN + wave * 8;

    int idx[8];
#pragma unroll
    for (int j = 0; j < 8; ++j) idx[j] = midx[j];

    float acc[8];
#pragma unroll
    for (int j = 0; j < 8; ++j) {
        const float* w = weight + (size_t)idx[j] * HIDDEN + lane * 8;
        const float4 a = *(const float4*)(w);
        const float4 b = *(const float4*)(w + 4);
        acc[j] = x0.x * a.x + x0.y * a.y + x0.z * a.z + x0.w * a.w
               + x1.x * b.x + x1.y * b.y + x1.z * b.z + x1.w * b.w;
    }
#pragma unroll
    for (int j = 0; j < 8; ++j) {
        float p = acc[j];
#pragma unroll
        for (int off = 32; off > 0; off >>= 1)
            p += __shfl_down(p, off, 64);
        if (lane == 0) {
            float v = p + bias[idx[j]];
            orow[j] = v > 0.0f ? v : 0.0f;
        }
    }
}

extern "C" void kernel_launch(void* const* d_in, const int* in_sizes, int n_in,
                              void* d_out, int out_size, void* d_ws, size_t ws_size,
                              hipStream_t stream) {
    const float* input  = (const float*)d_in[0];   // [4,2048,512] fp32
    const int*   mask   = (const int*)  d_in[1];   // [4,2048,32] int32
    const float* weight = (const float*)d_in[2];   // [50000,512] fp32
    const float* bias   = (const float*)d_in[3];   // [50000] fp32
    float*       out    = (float*)d_out;           // [4,2048,32] fp32

    const int n_tokens = in_sizes[0] / HIDDEN;     // 8192
    const int n_pairs  = in_sizes[1];              // 262144
    const int n_rows   = in_sizes[2] / HIDDEN;     // 50000

    // Workspace layout (all 16B-aligned):
    const size_t in_h_bytes   = (size_t)in_sizes[0] * sizeof(_Float16); // 8.4MB
    const size_t counts_bytes = (size_t)n_rows * sizeof(int);           // 200KB
    const size_t padded_bytes = (size_t)n_rows * BUCKET_CAP * sizeof(int); // 6.4MB
    const size_t need = in_h_bytes + counts_bytes + padded_bytes;

    if (ws_size >= need) {
        _Float16* in_h   = (_Float16*)d_ws;
        int*      counts = (int*)((char*)d_ws + in_h_bytes);
        int*      padded = (int*)((char*)d_ws + in_h_bytes + counts_bytes);

        const int n_chunks = in_sizes[0] / 8;      // 524288
        int g1 = (n_chunks + 255) / 256;           // covers zeroing too (50000 < n_chunks)
        prep_kernel<<<g1, 256, 0, stream>>>(input, in_h, counts, n_chunks, n_rows);

        scatter_kernel<<<(n_pairs + 255) / 256, 256, 0, stream>>>(
            mask, counts, padded, n_pairs);

        const int n_wave_rows   = (n_rows + 3) / 4;          // rows per block = 4
        const int blocks_per_xcd = (n_wave_rows + 7) / 8;    // 1563
        const int grid = blocks_per_xcd * 8;                 // 12504
        row_ffn_kernel<<<grid, 256, 0, stream>>>(
            in_h, weight, bias, counts, padded, out, n_rows, blocks_per_xcd);
    } else {
        dynamic_ffn_f32_kernel<<<n_tokens, 256, 0, stream>>>(
            input, mask, weight, bias, out, n_tokens);
    }
}

// Round 6
// 202.469 us; speedup vs baseline: 1.0856x; 1.0141x over previous
//
#include <hip/hip_runtime.h>
#include <hip/hip_bf16.h>

#define HIDDEN 512
#define M_PER_TOKEN 32
#define BUCKET_CAP 32   // Poisson(5.24) users/row; P(>32) ~ 1e-11 for 50k rows

typedef _Float16 half8 __attribute__((ext_vector_type(8)));

// ---------------------------------------------------------------------------
// K1: input fp32 -> fp16 (8.4 MB gathered-side table) + zero counts.
// ---------------------------------------------------------------------------
__global__ __launch_bounds__(256) void prep_kernel(
    const float* __restrict__ input,   // [8192*512]
    _Float16*    __restrict__ in_h,    // [8192*512]
    int*         __restrict__ counts,  // [n_rows]
    int n_chunks, int n_rows)
{
    int i = blockIdx.x * 256 + threadIdx.x;
    if (i < n_chunks) {
        const float4 a = ((const float4*)input)[2 * i];
        const float4 b = ((const float4*)input)[2 * i + 1];
        half8 h;
        h[0] = (_Float16)a.x; h[1] = (_Float16)a.y;
        h[2] = (_Float16)a.z; h[3] = (_Float16)a.w;
        h[4] = (_Float16)b.x; h[5] = (_Float16)b.y;
        h[6] = (_Float16)b.z; h[7] = (_Float16)b.w;
        ((half8*)in_h)[i] = h;
    }
    if (i < n_rows) counts[i] = 0;
}

// ---------------------------------------------------------------------------
// K2: inverted index. pair i -> row r = mask[i]; bucket slot via atomicAdd.
// ---------------------------------------------------------------------------
__global__ __launch_bounds__(256) void scatter_kernel(
    const int* __restrict__ mask,     // [262144]
    int*       __restrict__ counts,   // [n_rows]
    int*       __restrict__ padded,   // [n_rows*32]
    int n_pairs)
{
    int i = blockIdx.x * 256 + threadIdx.x;
    if (i >= n_pairs) return;
    int r = mask[i];
    int slot = atomicAdd(&counts[r], 1);
    if (slot < BUCKET_CAP) padded[(r << 5) + slot] = i;
}

// ---------------------------------------------------------------------------
// K3 v6: row-centric, QUARTER-WAVE users.
// One wave per weight row; 16 lanes per user, 4 users processed per group:
//  - sublane s owns elements {j*128 + s*8 : j=0..3} of both weight (fp32
//    regs, same for all quarters -> L1 broadcast) and the user's fp16 row
//    (4 x half8 gather, per-j 256B contiguous per quarter).
//  - reduce = 4 shuffle levels across 16 lanes, SHARED by 4 users
//    (1 DS op/user vs 6 in v5 -- v5's measured wall: 22% VALUBusy dominated
//    by per-user 6-level ds_bpermute chains).
// ---------------------------------------------------------------------------
__global__ __launch_bounds__(256) void row_ffn_kernel(
    const _Float16* __restrict__ in_h,    // [8192, 512] fp16
    const float*    __restrict__ weight,  // [n_rows, 512] fp32
    const float*    __restrict__ bias,    // [n_rows]
    const int*      __restrict__ counts,  // [n_rows]
    const int*      __restrict__ padded,  // [n_rows, 32]
    float*          __restrict__ out,     // [8192, 32]
    int n_rows, int blocks_per_xcd)
{
    const int b    = (int)blockIdx.x;
    const int bsw  = (b & 7) * blocks_per_xcd + (b >> 3);  // XCD-contiguous
    const int wave = threadIdx.x >> 6;
    const int lane = threadIdx.x & 63;
    const int s    = lane & 15;   // sublane within quarter
    const int q    = lane >> 4;   // quarter = which user of the group
    const int r    = bsw * 4 + wave;
    if (r >= n_rows) return;

    int c = counts[r];
    if (c <= 0) return;
    if (c > BUCKET_CAP) c = BUCKET_CAP;

    // Weight row (streamed once, sequential across waves/blocks).
    // Lane's 32 elements as 8 float4; all 4 quarters read identical addrs.
    const float* wbase = weight + (size_t)r * HIDDEN + s * 8;
    float4 w[8];
#pragma unroll
    for (int j = 0; j < 4; ++j) {
        w[2 * j]     = *(const float4*)(wbase + j * 128);
        w[2 * j + 1] = *(const float4*)(wbase + j * 128 + 4);
    }
    const float bv    = bias[r];
    const int*  users = padded + (r << 5);

    for (int u = 0; u < c; u += 4) {
        const int g   = c - u;                    // users left (>=1)
        const int off = (q < g) ? q : (g - 1);    // duplicate last for idle quarters
        const int pid = users[u + off];           // pair index; token = pid>>5

        const _Float16* irow = in_h + (size_t)(pid >> 5) * HIDDEN + s * 8;
        const half8 h0 = *(const half8*)(irow);
        const half8 h1 = *(const half8*)(irow + 128);
        const half8 h2 = *(const half8*)(irow + 256);
        const half8 h3 = *(const half8*)(irow + 384);

        float d0 = (float)h0[0]*w[0].x + (float)h0[1]*w[0].y
                 + (float)h0[2]*w[0].z + (float)h0[3]*w[0].w
                 + (float)h0[4]*w[1].x + (float)h0[5]*w[1].y
                 + (float)h0[6]*w[1].z + (float)h0[7]*w[1].w;
        float d1 = (float)h1[0]*w[2].x + (float)h1[1]*w[2].y
                 + (float)h1[2]*w[2].z + (float)h1[3]*w[2].w
                 + (float)h1[4]*w[3].x + (float)h1[5]*w[3].y
                 + (float)h1[6]*w[3].z + (float)h1[7]*w[3].w;
        float d2 = (float)h2[0]*w[4].x + (float)h2[1]*w[4].y
                 + (float)h2[2]*w[4].z + (float)h2[3]*w[4].w
                 + (float)h2[4]*w[5].x + (float)h2[5]*w[5].y
                 + (float)h2[6]*w[5].z + (float)h2[7]*w[5].w;
        float d3 = (float)h3[0]*w[6].x + (float)h3[1]*w[6].y
                 + (float)h3[2]*w[6].z + (float)h3[3]*w[6].w
                 + (float)h3[4]*w[7].x + (float)h3[5]*w[7].y
                 + (float)h3[6]*w[7].z + (float)h3[7]*w[7].w;
        float d = (d0 + d1) + (d2 + d3);

        // 16-lane reduce, all 4 quarters (users) in the same 4 DS ops.
        d += __shfl_down(d, 8, 16);
        d += __shfl_down(d, 4, 16);
        d += __shfl_down(d, 2, 16);
        d += __shfl_down(d, 1, 16);

        if (s == 0 && q < g) {
            float v = d + bv;
            out[pid] = v > 0.0f ? v : 0.0f;
        }
    }
}

// ---------------------------------------------------------------------------
// Fallback (ws too small): round-1 fp32 token-centric, known-good 97us.
// ---------------------------------------------------------------------------
__global__ __launch_bounds__(256) void dynamic_ffn_f32_kernel(
    const float* __restrict__ input,
    const int*   __restrict__ mask,
    const float* __restrict__ weight,
    const float* __restrict__ bias,
    float*       __restrict__ out,
    int n_tokens)
{
    const int token = blockIdx.x;
    if (token >= n_tokens) return;
    const int wave = threadIdx.x >> 6;
    const int lane = threadIdx.x & 63;

    const float* in_row = input + (size_t)token * HIDDEN + lane * 8;
    const float4 x0 = *(const float4*)(in_row);
    const float4 x1 = *(const float4*)(in_row + 4);

    const int* midx = mask + (size_t)token * M_PER_TOKEN + wave * 8;
    float*     orow = out  + (size_t)token * M_PER_TOKEN + wave * 8;

    int idx[8];
#pragma unroll
    for (int j = 0; j < 8; ++j) idx[j] = midx[j];

    float acc[8];
#pragma unroll
    for (int j = 0; j < 8; ++j) {
        const float* w = weight + (size_t)idx[j] * HIDDEN + lane * 8;
        const float4 a = *(const float4*)(w);
        const float4 b = *(const float4*)(w + 4);
        acc[j] = x0.x * a.x + x0.y * a.y + x0.z * a.z + x0.w * a.w
               + x1.x * b.x + x1.y * b.y + x1.z * b.z + x1.w * b.w;
    }
#pragma unroll
    for (int j = 0; j < 8; ++j) {
        float p = acc[j];
#pragma unroll
        for (int off = 32; off > 0; off >>= 1)
            p += __shfl_down(p, off, 64);
        if (lane == 0) {
            float v = p + bias[idx[j]];
            orow[j] = v > 0.0f ? v : 0.0f;
        }
    }
}

extern "C" void kernel_launch(void* const* d_in, const int* in_sizes, int n_in,
                              void* d_out, int out_size, void* d_ws, size_t ws_size,
                              hipStream_t stream) {
    const float* input  = (const float*)d_in[0];   // [4,2048,512] fp32
    const int*   mask   = (const int*)  d_in[1];   // [4,2048,32] int32
    const float* weight = (const float*)d_in[2];   // [50000,512] fp32
    const float* bias   = (const float*)d_in[3];   // [50000] fp32
    float*       out    = (float*)d_out;           // [4,2048,32] fp32

    const int n_tokens = in_sizes[0] / HIDDEN;     // 8192
    const int n_pairs  = in_sizes[1];              // 262144
    const int n_rows   = in_sizes[2] / HIDDEN;     // 50000

    const size_t in_h_bytes   = (size_t)in_sizes[0] * sizeof(_Float16);    // 8.4MB
    const size_t counts_bytes = (size_t)n_rows * sizeof(int);              // 200KB
    const size_t padded_bytes = (size_t)n_rows * BUCKET_CAP * sizeof(int); // 6.4MB
    const size_t need = in_h_bytes + counts_bytes + padded_bytes;

    if (ws_size >= need) {
        _Float16* in_h   = (_Float16*)d_ws;
        int*      counts = (int*)((char*)d_ws + in_h_bytes);
        int*      padded = (int*)((char*)d_ws + in_h_bytes + counts_bytes);

        const int n_chunks = in_sizes[0] / 8;      // 524288
        prep_kernel<<<(n_chunks + 255) / 256, 256, 0, stream>>>(
            input, in_h, counts, n_chunks, n_rows);

        scatter_kernel<<<(n_pairs + 255) / 256, 256, 0, stream>>>(
            mask, counts, padded, n_pairs);

        const int n_wave_rows    = (n_rows + 3) / 4;         // 12500
        const int blocks_per_xcd = (n_wave_rows + 7) / 8;    // 1563
        const int grid           = blocks_per_xcd * 8;       // 12504
        row_ffn_kernel<<<grid, 256, 0, stream>>>(
            in_h, weight, bias, counts, padded, out, n_rows, blocks_per_xcd);
    } else {
        dynamic_ffn_f32_kernel<<<n_tokens, 256, 0, stream>>>(
            input, mask, weight, bias, out, n_tokens);
    }
}